// Round 5
// baseline (210.532 us; speedup 1.0000x reference)
//
#include <hip/hip_runtime.h>
#include <math.h>

#define NROWS  (1024 * 4096)        // 2^22 rows of 8 floats
#define E      (NROWS * 2)          // 2^23 float4s in x
#define BLOCKS 2048
#define TPB    256
#define RP     16                   // float4s per thread: BLOCKS*TPB*RP == E
#define NW     (TPB / 64)

__global__ __launch_bounds__(TPB) void penalty_main(
        const float* __restrict__ x,
        const float* __restrict__ min_,
        const float* __restrict__ scale_,
        unsigned int* __restrict__ part) {
    const float min2 = min_[2], min3 = min_[3];
    const float sc2  = scale_[2], sc3 = scale_[3];

    const int tid  = threadIdx.x;
    const int lane = tid & 63;
    const int wave = tid >> 6;
    const unsigned G = BLOCKS * TPB;            // 2^19 threads
    const unsigned t = blockIdx.x * TPB + tid;  // first float4 index
    // G is even -> idx parity == t parity, constant per thread.
    const bool even = ((t & 1u) == 0u);

    // ---- phase 1: DENSE lane-contiguous float4 loads (1 KB/wave-instr) ----
    const float4* __restrict__ x4 = (const float4*)x;
    float4 v[RP];
    #pragma unroll
    for (int r = 0; r < RP; ++r) v[r] = x4[t + (unsigned)r * G];
    asm volatile("" ::: "memory");   // keep all 16 in flight

    // ---- phase 2: even threads own row idx/2; cols 2,3 are .z/.w ----
    float a[RP];
    unsigned c1 = 0, c2 = 0, c4 = 0;
    #pragma unroll
    for (int r = 0; r < RP; ++r) {
        const float d = (v[r].z - min2) / sc2;
        a[r] = (v[r].w - min3) / sc3;
        if (even) {
            c1 += !(d >= 0.0f && d <= 252.0f);
            c2 += (a[r] < 0.0f) || (a[r] > 22.0f);
            c4 += (a[r] != 22.0f);
        }
    }

    // ---- cross-wave handoff: lane 0 (even) of each wave publishes a[] ----
    __shared__ float sA[NW][RP];
    if (lane == 0) {
        #pragma unroll
        for (int r = 0; r < RP; ++r) sA[wave][r] = a[r];
    }
    __syncthreads();

    // tid==254 (lane 62 of last wave): neighbor is next block's first float4
    float abound[RP];
    if (tid == TPB - 2) {
        #pragma unroll
        for (int r = 0; r < RP; ++r) {
            const unsigned idx2 = t + (unsigned)r * G + 2u;
            abound[r] = (idx2 < (unsigned)E)
                      ? (x[4u * idx2 + 3u] - min3) / sc3 : 0.0f;
        }
    }

    // ---- transition penalty: next row's a is 2 lanes down ----
    unsigned c3 = 0;
    #pragma unroll
    for (int r = 0; r < RP; ++r) {
        float an = __shfl_down(a[r], 2);
        if (lane == 62) an = (wave < NW - 1) ? sA[wave + 1][r] : abound[r];
        if (even) {
            const unsigned idx = t + (unsigned)r * G;
            const bool cond = (fmodf(a[r], 2.0f) == 0.0f) && (a[r] < 20.0f)
                              && (idx + 2u < (unsigned)E);   // == (row+1 < NROWS)
            const bool invalid = (an != a[r] + 1.0f) && (an != 22.0f);
            c3 += (cond && invalid);
        }
    }

    // ---- block reduction, plain stores ----
    for (int off = 32; off > 0; off >>= 1) {
        c1 += __shfl_down(c1, off);
        c2 += __shfl_down(c2, off);
        c3 += __shfl_down(c3, off);
        c4 += __shfl_down(c4, off);
    }
    __shared__ unsigned int s[NW][4];
    if (lane == 0) { s[wave][0] = c1; s[wave][1] = c2; s[wave][2] = c3; s[wave][3] = c4; }
    __syncthreads();
    if (tid == 0) {
        unsigned t1 = 0, t2 = 0, t3 = 0, t4 = 0;
        #pragma unroll
        for (int w = 0; w < NW; ++w) {
            t1 += s[w][0]; t2 += s[w][1]; t3 += s[w][2]; t4 += s[w][3];
        }
        unsigned int* p = part + 4u * blockIdx.x;
        p[0] = t1; p[1] = t2; p[2] = t3; p[3] = t4;
    }
}

__global__ __launch_bounds__(TPB) void finalize(
        const unsigned int* __restrict__ part, float* __restrict__ out) {
    const int tid = threadIdx.x;
    unsigned c1 = 0, c2 = 0, c3 = 0, c4 = 0;
    for (int b = tid; b < BLOCKS; b += TPB) {
        const unsigned int* p = part + 4 * b;
        c1 += p[0]; c2 += p[1]; c3 += p[2]; c4 += p[3];
    }
    for (int off = 32; off > 0; off >>= 1) {
        c1 += __shfl_down(c1, off);
        c2 += __shfl_down(c2, off);
        c3 += __shfl_down(c3, off);
        c4 += __shfl_down(c4, off);
    }
    __shared__ unsigned int s[NW][4];
    const int lane = tid & 63, wave = tid >> 6;
    if (lane == 0) { s[wave][0] = c1; s[wave][1] = c2; s[wave][2] = c3; s[wave][3] = c4; }
    __syncthreads();
    if (tid == 0) {
        unsigned t1 = 0, t2 = 0, t3 = 0, t4 = 0;
        #pragma unroll
        for (int w = 0; w < NW; ++w) {
            t1 += s[w][0]; t2 += s[w][1]; t3 += s[w][2]; t4 += s[w][3];
        }
        out[0] = (float)t1 + (float)t2 + (float)t3
               + fabsf((float)t4 - 58.0f);
    }
}

extern "C" void kernel_launch(void* const* d_in, const int* in_sizes, int n_in,
                              void* d_out, int out_size, void* d_ws, size_t ws_size,
                              hipStream_t stream) {
    const float* x  = (const float*)d_in[0];
    const float* mn = (const float*)d_in[1];
    const float* sc = (const float*)d_in[2];
    unsigned int* part = (unsigned int*)d_ws;   // BLOCKS*4 uints = 32 KB
    float* out = (float*)d_out;

    penalty_main<<<BLOCKS, TPB, 0, stream>>>(x, mn, sc, part);
    finalize<<<1, TPB, 0, stream>>>(part, out);
}

// Round 6
// 208.610 us; speedup vs baseline: 1.0092x; 1.0092x over previous
//
#include <hip/hip_runtime.h>
#include <math.h>

#define NROWS  (1024 * 4096)        // 2^22 rows of 8 floats
#define E      (NROWS * 2)          // 2^23 float4s in x
#define BLOCKS 4096
#define TPB    256
#define RP     8                    // float4s per thread: BLOCKS*TPB*RP == E
#define NW     (TPB / 64)

typedef float vf4 __attribute__((ext_vector_type(4)));

__global__ __launch_bounds__(TPB) void penalty_main(
        const float* __restrict__ x,
        const float* __restrict__ min_,
        const float* __restrict__ scale_,
        unsigned int* __restrict__ part) {
    const float min2 = min_[2], min3 = min_[3];
    const float sc2  = scale_[2], sc3 = scale_[3];

    const int tid  = threadIdx.x;
    const int lane = tid & 63;
    const int wave = tid >> 6;
    const unsigned G = BLOCKS * TPB;            // 2^20 threads
    const unsigned t = blockIdx.x * TPB + tid;  // first float4 index
    const bool even = ((t & 1u) == 0u);         // G even -> parity constant

    // byte offsets of the 8 float4s this thread loads (stride G*16 = 16 MB)
    unsigned o0 = t * 16u;
    unsigned o1 = o0 + 1u * (G * 16u);
    unsigned o2 = o0 + 2u * (G * 16u);
    unsigned o3 = o0 + 3u * (G * 16u);
    unsigned o4 = o0 + 4u * (G * 16u);
    unsigned o5 = o0 + 5u * (G * 16u);
    unsigned o6 = o0 + 6u * (G * 16u);
    unsigned o7 = o0 + 7u * (G * 16u);

    // ---- monolithic load batch: 8 dense dwordx4 loads, ONE waitcnt ----
    // The compiler cannot narrow/sink/split an asm block: 8 x 1KB wave-loads
    // genuinely in flight (m13 copy pattern), results pinned in 32 VGPRs.
    vf4 v0, v1, v2, v3, v4, v5, v6, v7;
    asm volatile(
        "global_load_dwordx4 %0, %8,  %16\n\t"
        "global_load_dwordx4 %1, %9,  %16\n\t"
        "global_load_dwordx4 %2, %10, %16\n\t"
        "global_load_dwordx4 %3, %11, %16\n\t"
        "global_load_dwordx4 %4, %12, %16\n\t"
        "global_load_dwordx4 %5, %13, %16\n\t"
        "global_load_dwordx4 %6, %14, %16\n\t"
        "global_load_dwordx4 %7, %15, %16\n\t"
        "s_waitcnt vmcnt(0)"
        : "=v"(v0), "=v"(v1), "=v"(v2), "=v"(v3),
          "=v"(v4), "=v"(v5), "=v"(v6), "=v"(v7)
        : "v"(o0), "v"(o1), "v"(o2), "v"(o3),
          "v"(o4), "v"(o5), "v"(o6), "v"(o7),
          "s"(x)
        : "memory");

    vf4 v[RP] = {v0, v1, v2, v3, v4, v5, v6, v7};

    // ---- even threads own row idx/2; cols 2,3 are .z/.w ----
    float a[RP];
    unsigned c1 = 0, c2 = 0, c4 = 0;
    #pragma unroll
    for (int r = 0; r < RP; ++r) {
        const float d = (v[r].z - min2) / sc2;
        a[r] = (v[r].w - min3) / sc3;
        if (even) {
            c1 += !(d >= 0.0f && d <= 252.0f);
            c2 += (a[r] < 0.0f) || (a[r] > 22.0f);
            c4 += (a[r] != 22.0f);
        }
    }

    // ---- cross-wave handoff: lane 0 of each wave publishes a[] ----
    __shared__ float sA[NW][RP];
    if (lane == 0) {
        #pragma unroll
        for (int r = 0; r < RP; ++r) sA[wave][r] = a[r];
    }
    __syncthreads();

    // tid==254 (lane 62, last wave): neighbor is next block's first float4
    float abound[RP];
    if (tid == TPB - 2) {
        #pragma unroll
        for (int r = 0; r < RP; ++r) {
            const unsigned idx2 = t + (unsigned)r * G + 2u;
            abound[r] = (idx2 < (unsigned)E)
                      ? (x[4u * idx2 + 3u] - min3) / sc3 : 0.0f;
        }
    }

    // ---- transition penalty: next row's a is 2 lanes down ----
    unsigned c3 = 0;
    #pragma unroll
    for (int r = 0; r < RP; ++r) {
        float an = __shfl_down(a[r], 2);
        if (lane == 62) an = (wave < NW - 1) ? sA[wave + 1][r] : abound[r];
        if (even) {
            const unsigned idx = t + (unsigned)r * G;
            const bool cond = (fmodf(a[r], 2.0f) == 0.0f) && (a[r] < 20.0f)
                              && (idx + 2u < (unsigned)E);  // row+1 < NROWS
            const bool invalid = (an != a[r] + 1.0f) && (an != 22.0f);
            c3 += (cond && invalid);
        }
    }

    // ---- block reduction, plain stores ----
    for (int off = 32; off > 0; off >>= 1) {
        c1 += __shfl_down(c1, off);
        c2 += __shfl_down(c2, off);
        c3 += __shfl_down(c3, off);
        c4 += __shfl_down(c4, off);
    }
    __shared__ unsigned int s[NW][4];
    if (lane == 0) { s[wave][0] = c1; s[wave][1] = c2; s[wave][2] = c3; s[wave][3] = c4; }
    __syncthreads();
    if (tid == 0) {
        unsigned t1 = 0, t2 = 0, t3 = 0, t4 = 0;
        #pragma unroll
        for (int w = 0; w < NW; ++w) {
            t1 += s[w][0]; t2 += s[w][1]; t3 += s[w][2]; t4 += s[w][3];
        }
        unsigned int* p = part + 4u * blockIdx.x;
        p[0] = t1; p[1] = t2; p[2] = t3; p[3] = t4;
    }
}

__global__ __launch_bounds__(TPB) void finalize(
        const unsigned int* __restrict__ part, float* __restrict__ out) {
    const int tid = threadIdx.x;
    unsigned c1 = 0, c2 = 0, c3 = 0, c4 = 0;
    for (int b = tid; b < BLOCKS; b += TPB) {
        const unsigned int* p = part + 4 * b;
        c1 += p[0]; c2 += p[1]; c3 += p[2]; c4 += p[3];
    }
    for (int off = 32; off > 0; off >>= 1) {
        c1 += __shfl_down(c1, off);
        c2 += __shfl_down(c2, off);
        c3 += __shfl_down(c3, off);
        c4 += __shfl_down(c4, off);
    }
    __shared__ unsigned int s[NW][4];
    const int lane = tid & 63, wave = tid >> 6;
    if (lane == 0) { s[wave][0] = c1; s[wave][1] = c2; s[wave][2] = c3; s[wave][3] = c4; }
    __syncthreads();
    if (tid == 0) {
        unsigned t1 = 0, t2 = 0, t3 = 0, t4 = 0;
        #pragma unroll
        for (int w = 0; w < NW; ++w) {
            t1 += s[w][0]; t2 += s[w][1]; t3 += s[w][2]; t4 += s[w][3];
        }
        out[0] = (float)t1 + (float)t2 + (float)t3
               + fabsf((float)t4 - 58.0f);
    }
}

extern "C" void kernel_launch(void* const* d_in, const int* in_sizes, int n_in,
                              void* d_out, int out_size, void* d_ws, size_t ws_size,
                              hipStream_t stream) {
    const float* x  = (const float*)d_in[0];
    const float* mn = (const float*)d_in[1];
    const float* sc = (const float*)d_in[2];
    unsigned int* part = (unsigned int*)d_ws;   // BLOCKS*4 uints = 64 KB
    float* out = (float*)d_out;

    penalty_main<<<BLOCKS, TPB, 0, stream>>>(x, mn, sc, part);
    finalize<<<1, TPB, 0, stream>>>(part, out);
}